// Round 17
// baseline (132.245 us; speedup 1.0000x reference)
//
#include <hip/hip_runtime.h>
#include <hip/hip_bf16.h>
#include <math.h>

// Problem constants (B=8, H=W=256, C=32, WIN=8, HEADS=2, DH=16, HIDDEN=128)
#define IMG   256
#define HWTOK 65536
#define CH    32

typedef __attribute__((ext_vector_type(8))) _Float16 half8v;    // 8 fp16
typedef __attribute__((ext_vector_type(2))) _Float16 half2v;    // 2 fp16
typedef __attribute__((ext_vector_type(4))) float floatx4;

__device__ __forceinline__ unsigned short f2h(float f) {
    _Float16 h = (_Float16)f;
    return __builtin_bit_cast(unsigned short, h);
}
__device__ __forceinline__ half2v pkrtz(float a, float b) {
    return __builtin_bit_cast(half2v, __builtin_amdgcn_cvt_pkrtz(a, b));
}
__device__ __forceinline__ unsigned packh2(float a, float b) {
    return __builtin_bit_cast(unsigned, __builtin_amdgcn_cvt_pkrtz(a, b));
}
// 16B fragment loads from LDS rows whose stride only guarantees 4B / 8B align.
__device__ __forceinline__ half8v ld8_b32(const unsigned short* p) {
    uint4 u;
    u.x = *(const unsigned*)(p + 0);
    u.y = *(const unsigned*)(p + 2);
    u.z = *(const unsigned*)(p + 4);
    u.w = *(const unsigned*)(p + 6);
    return __builtin_bit_cast(half8v, u);
}
__device__ __forceinline__ half8v ld8_b64(const unsigned short* p) {
    const uint2 a = *(const uint2*)(p + 0);
    const uint2 b = *(const uint2*)(p + 4);
    uint4 u; u.x = a.x; u.y = a.y; u.z = b.x; u.w = b.y;
    return __builtin_bit_cast(half8v, u);
}

// GELU via odd Taylor of Phi(v) = 0.5 + v*p(v^2), packed fp16.
__device__ __forceinline__ half2v gelu2v(half2v v) {
    const half2v hi = (half2v)(_Float16)( 2.0f);
    const half2v lo = (half2v)(_Float16)(-2.0f);
    const half2v vc = __builtin_elementwise_min(__builtin_elementwise_max(v, lo), hi);
    const half2v s  = vc * vc;
    half2v p = s * (half2v)(_Float16)(-1.18726e-3f) + (half2v)(_Float16)(9.97356e-3f);
    p = s * p + (half2v)(_Float16)(-6.64904e-2f);
    p = s * p + (half2v)(_Float16)( 3.989423e-1f);
    return v * (vc * p + (half2v)(_Float16)(0.5f));
}

// ---------------------------------------------------------------------------
// Prep: one-shot marshalling into workspace (29 blocks x 256). (unchanged)
// ---------------------------------------------------------------------------
__global__ __launch_bounds__(256) void prep_kernel(
    const float* __restrict__ w1, const float* __restrict__ w2,
    const float* __restrict__ wq, const float* __restrict__ wkv,
    const float* __restrict__ wo, const float* __restrict__ dw,
    const float* __restrict__ dwb, const float* __restrict__ relb,
    unsigned short* __restrict__ w1p, unsigned short* __restrict__ w2p,
    unsigned short* __restrict__ wqp, unsigned short* __restrict__ wkp,
    unsigned short* __restrict__ wvp, unsigned short* __restrict__ wop,
    unsigned short* __restrict__ dwp, unsigned short* __restrict__ dwbp,
    float* __restrict__ biasf)
{
    const float LOG2E = 1.4426950408889634f;
    const float QSC   = 0.25f * LOG2E;
    const int bid = blockIdx.x, tid = threadIdx.x;

    if (bid < 16) {                       // leff FC weights
        const int t = bid * 256 + tid;
        const int row = t >> 5, k = t & 31;
        const int bl = row >> 5, wi = row & 31;
        const int j = bl * 32 + ((wi & 15) << 1) + (wi >> 4);
        w1p[t] = f2h(w1[k * 128 + j]);
        const int n = t >> 7, kk = t & 127;
        w2p[t] = f2h(w2[kk * 32 + n]);
    } else if (bid < 20) {                // attn weights, frag layout
        const int u = (bid - 16) * 256 + tid;
        const int h = u >> 9, rem = u & 511;
        const int col = rem >> 5, k = rem & 31;
        wqp[u] = f2h(wq [k * 32 + h * 16 + col] * QSC);
        wkp[u] = f2h(wkv[k * 64 + h * 16 + col]);
        wvp[u] = f2h(wkv[k * 64 + 32 + h * 16 + col]);
        const int n = u >> 5, kk2 = u & 31;
        wop[u] = f2h(wo[kk2 * 32 + n]);
    } else if (bid < 28) {                // bias C-fragment table
        const int g = (bid - 20) * 256 + tid;
        const int h = g >> 10, nt = (g >> 8) & 3, mt = (g >> 6) & 3, l = g & 63;
        const int q = nt * 16 + (l & 15);
        const int mb = mt * 16 + (l >> 4) * 4;
        const int qy = q >> 3, qx = q & 7;
        #pragma unroll
        for (int r = 0; r < 4; ++r) {
            const int m = mb + r;
            const int my = m >> 3, mx = m & 7;
            const int idx = (qy - my + 7) * 15 + (qx - mx + 7);
            biasf[g * 4 + r] = relb[idx * 2 + h] * LOG2E;
        }
    } else {                              // dw pack
        for (int e = tid; e < 1280; e += 256) {
            if (e < 1152) dwp[e] = f2h(dw[(e & 127) * 9 + (e >> 7)]);
            else          dwbp[e - 1152] = f2h(dwb[e - 1152]);
        }
    }
}

// ---------------------------------------------------------------------------
// Kernel 1: LN1 + window attention + proj + residual.
// ONE window per 256-thread block (4 waves = (head h, half s2)).
// LDS squeezed to EXACTLY 32,768 B -> 4 blocks/CU under the 128 KB pool
// model (was 34,816 -> 3 blocks).  Strides: xn/O/Q 38, P 68, K 48, VT 68;
// fragment loads use b64/b32 splits where 16B alignment is lost.  denom
// aliases the dead Q region (barrier added after S^T fragment loads).
// ---------------------------------------------------------------------------
__global__ __launch_bounds__(256, 4) void attn_kernel(
    const float* __restrict__ x,
    const float* __restrict__ n1g, const float* __restrict__ n1b,
    const float* __restrict__ bq,  const float* __restrict__ bkv,
    const float* __restrict__ bo,
    const unsigned short* __restrict__ wqp,
    const unsigned short* __restrict__ wkp,
    const unsigned short* __restrict__ wvp,
    const unsigned short* __restrict__ wop,
    const float4* __restrict__ biasf4,
    float* __restrict__ x1)
{
    struct Win {
        union {
            unsigned short xn[64][38];    // 4864
            unsigned short P[2][64][68];  // 17408 (max member)
            unsigned short O[64][38];
        } u;
        unsigned short Q[64][38];         // 4864 (denom aliases after S^T loads)
        unsigned short K[64][48];         // 6144 (cols 16..31 zero mask)
        unsigned short VT[2][16][68];     // 4352
    };                                    // total 32768 B exactly
    __shared__ __align__(16) Win S;

    const int tid = threadIdx.x;
    const int wv  = tid >> 6;             // wave 0..3
    const int h   = wv & 1;               // head
    const int s2  = wv >> 1;              // half: mt/nt in {2*s2, 2*s2+1}
    const int l   = tid & 63;
    const int lm  = l & 15, lq = l >> 4;

    const int win = blockIdx.x;
    const int b   = win >> 10;
    const int wh  = (win >> 5) & 31, ww = win & 31;
    const size_t wbase = ((size_t)b * HWTOK + (wh * 8) * IMG + ww * 8) * CH;

    const float LOG2E = 1.4426950408889634f;
    const float QSC   = 0.25f * LOG2E;

    // ---- weight B-frags: single b128 loads from prepped tables ----
    const half8v bwq  = *(const half8v*)&wqp[h * 512 + lm * 32 + lq * 8];
    const half8v bwk  = *(const half8v*)&wkp[h * 512 + lm * 32 + lq * 8];
    const half8v bwv  = *(const half8v*)&wvp[h * 512 + lm * 32 + lq * 8];
    const half8v bwo0 = *(const half8v*)&wop[lm * 32 + lq * 8];
    const half8v bwo1 = *(const half8v*)&wop[(16 + lm) * 32 + lq * 8];

    // ---- LN staging: 4 threads per token (8 ch each, 2-level shfl) ----
    {
        const int tok = tid >> 2, q4 = tid & 3;
        const size_t sbase = wbase
            + (size_t)((tok >> 3) * IMG + (tok & 7)) * CH + q4 * 8;
        const float4* xp = (const float4*)(x + sbase);
        float v[8];
        float s = 0.f;
        #pragma unroll
        for (int i = 0; i < 2; ++i) {
            const float4 t = xp[i];
            v[i*4+0]=t.x; v[i*4+1]=t.y; v[i*4+2]=t.z; v[i*4+3]=t.w;
            s += t.x + t.y + t.z + t.w;
        }
        s += __shfl_xor(s, 1);
        s += __shfl_xor(s, 2);
        const float mu = s * (1.f / 32.f);
        float qq = 0.f;
        #pragma unroll
        for (int c = 0; c < 8; ++c) { const float d = v[c] - mu; qq += d * d; }
        qq += __shfl_xor(qq, 1);
        qq += __shfl_xor(qq, 2);
        const float inv = rsqrtf(qq * (1.f / 32.f) + 1e-5f);
        #pragma unroll
        for (int j = 0; j < 4; ++j) {
            const int c = q4 * 8 + 2 * j;
            *(unsigned*)&S.u.xn[tok][c] =
                packh2((v[2*j]   - mu) * inv * n1g[c]   + n1b[c],
                       (v[2*j+1] - mu) * inv * n1g[c+1] + n1b[c+1]);
        }
        if (q4 < 2) {                                // zero K mask cols 16..31
            const uint4 z = {0u, 0u, 0u, 0u};
            *(uint4*)&S.K[tok][16 + q4 * 8] = z;     // 96tok+32+16q4: 16B ok
        }
    }
    __syncthreads();                               // (1) xn ready

    const float bqv = bq[h*16 + lm] * QSC;
    const float bkv_ = bkv[h*16 + lm];
    const float bvv = bkv[32 + h*16 + lm];
    const floatx4 cq = {bqv, bqv, bqv, bqv};
    const floatx4 ck = {bkv_, bkv_, bkv_, bkv_};
    const floatx4 cv = {bvv, bvv, bvv, bvv};
    const floatx4 zero = {0.f, 0.f, 0.f, 0.f};

    // ---- QKV projection (own head, own mt half) ----
    #pragma unroll
    for (int mi = 0; mi < 2; ++mi) {
        const int mt = 2*s2 + mi;
        const half8v a = ld8_b32(&S.u.xn[mt*16 + lm][lq*8]);
        const floatx4 dq = __builtin_amdgcn_mfma_f32_16x16x32_f16(a, bwq, cq, 0,0,0);
        const floatx4 dk = __builtin_amdgcn_mfma_f32_16x16x32_f16(a, bwk, ck, 0,0,0);
        const floatx4 dv = __builtin_amdgcn_mfma_f32_16x16x32_f16(a, bwv, cv, 0,0,0);
        const int r0 = mt*16 + lq*4;
        #pragma unroll
        for (int r = 0; r < 4; ++r) {
            S.Q[r0 + r][h*16 + lm] = f2h(dq[r]);
            S.K[r0 + r][h*32 + lm] = f2h(dk[r]);   // head h dims at cols 32h
        }
        uint2 vv;
        vv.x = packh2(dv[0], dv[1]);
        vv.y = packh2(dv[2], dv[3]);
        *(uint2*)&S.VT[h][lm][r0] = vv;            // 136lm+2r0: 8B aligned
    }
    __syncthreads();                               // (2) Q/K/V complete

    // ---- load S^T fragments, then free Q region for denom ----
    half8v ak[4], bqf[2];
    #pragma unroll
    for (int mt = 0; mt < 4; ++mt)
        ak[mt] = *(const half8v*)&S.K[mt*16 + lm][h*16 + lq*8];  // 96row: 16B ok
    #pragma unroll
    for (int ni = 0; ni < 2; ++ni)
        bqf[ni] = ld8_b32(&S.Q[(2*s2 + ni)*16 + lm][lq*8]);
    __syncthreads();                               // (3) frags in regs; Q dead

    float* denomQ = (float*)&S.Q[0][0];            // [h*64 + i]

    // ---- S^T = mfma(K, Q), rel_bias via C-init; own nt half ----
    #pragma unroll
    for (int ni = 0; ni < 2; ++ni) {
        const int nt = 2*s2 + ni;
        float sum = 0.f;
        #pragma unroll
        for (int mt = 0; mt < 4; ++mt) {
            const float4 cb = biasf4[(h*16 + nt*4 + mt) * 64 + l];
            const floatx4 C = {cb.x, cb.y, cb.z, cb.w};
            const floatx4 d = __builtin_amdgcn_mfma_f32_16x16x32_f16(ak[mt], bqf[ni], C, 0,0,0);
            const float e0 = exp2f(d[0]);
            const float e1 = exp2f(d[1]);
            const float e2 = exp2f(d[2]);
            const float e3 = exp2f(d[3]);
            sum += (e0 + e1) + (e2 + e3);
            uint2 pw;
            pw.x = packh2(e0, e1);
            pw.y = packh2(e2, e3);
            *(uint2*)&S.u.P[h][nt*16 + lm][mt*16 + lq*4] = pw;   // 8B aligned
        }
        sum += __shfl_xor(sum, 16);
        sum += __shfl_xor(sum, 32);
        if (l < 16) denomQ[h*64 + nt*16 + l] = __frcp_rn(sum);
    }

    // ---- PV + normalize (own mt half; P rows + denom are wave-local) ----
    const half8v bva = ld8_b64(&S.VT[h][lm][lq*8]);
    const half8v bvb = ld8_b64(&S.VT[h][lm][32 + lq*8]);
    float oreg[8];
    #pragma unroll
    for (int mi = 0; mi < 2; ++mi) {
        const int mt = 2*s2 + mi;
        const half8v ap0 = ld8_b64(&S.u.P[h][mt*16 + lm][lq*8]);
        const half8v ap1 = ld8_b64(&S.u.P[h][mt*16 + lm][32 + lq*8]);
        floatx4 ov = __builtin_amdgcn_mfma_f32_16x16x32_f16(ap0, bva, zero, 0,0,0);
        ov         = __builtin_amdgcn_mfma_f32_16x16x32_f16(ap1, bvb, ov,   0,0,0);
        const float4 dn = *(const float4*)&denomQ[h*64 + mt*16 + lq*4];
        oreg[mi*4+0] = ov[0] * dn.x;
        oreg[mi*4+1] = ov[1] * dn.y;
        oreg[mi*4+2] = ov[2] * dn.z;
        oreg[mi*4+3] = ov[3] * dn.w;
    }
    __syncthreads();                 // (4) PV reads done before O clobbers P

    #pragma unroll
    for (int mi = 0; mi < 2; ++mi) {
        const int mt = 2*s2 + mi;
        #pragma unroll
        for (int r = 0; r < 4; ++r)
            S.u.O[mt*16 + lq*4 + r][h*16 + lm] = f2h(oreg[mi*4 + r]);
    }
    __syncthreads();                 // (5) O complete

    // ---- out-projection + residual: wave wv handles mt = wv ----
    {
        const int mt = wv;
        const float bo0 = bo[lm], bo1 = bo[16 + lm];
        const floatx4 co0 = {bo0, bo0, bo0, bo0};
        const floatx4 co1 = {bo1, bo1, bo1, bo1};
        const half8v aO = ld8_b32(&S.u.O[mt*16 + lm][lq*8]);
        const floatx4 d0 = __builtin_amdgcn_mfma_f32_16x16x32_f16(aO, bwo0, co0, 0,0,0);
        const floatx4 d1 = __builtin_amdgcn_mfma_f32_16x16x32_f16(aO, bwo1, co1, 0,0,0);
        #pragma unroll
        for (int r = 0; r < 4; ++r) {
            const int t = mt*16 + lq*4 + r;
            const size_t g = wbase + (size_t)((t >> 3) * IMG + (t & 7)) * CH;
            x1[g + lm]      = x[g + lm]      + d0[r];
            x1[g + 16 + lm] = x[g + 16 + lm] + d1[r];
        }
    }
}

// ---------------------------------------------------------------------------
// Kernel 2: fused LeFF — 512 threads, LDS squeezed to 32,400 B (xnA stride 34,
// pad rows deleted: mt=6 A-frag reads spill into hid; the garbage only feeds
// MFMA D-rows p>=100 which are discarded) -> 4 blocks/CU = 32 waves = 100%.
// ---------------------------------------------------------------------------
__global__ __launch_bounds__(512, 8) void leff_kernel_gw(
    const float* __restrict__ x1,
    const float* __restrict__ n2g, const float* __restrict__ n2b,
    const float* __restrict__ b1,  const float* __restrict__ b2,
    const unsigned short* __restrict__ w1p,
    const unsigned short* __restrict__ w2p,
    const unsigned short* __restrict__ dwp,
    const unsigned short* __restrict__ dwbp,
    float* __restrict__ out)
{
    struct LeffS {
        unsigned short xnA[100][34];    // 6800 B (A-frag reads may spill ->hg)
        union {
            unsigned short hid[100][128];   // 25600 B
            unsigned short glA[64][132];    // 16896 B (inside hid region)
        } hg;
    };                                   // 32400 B total
    __shared__ __align__(16) LeffS LS;
    const unsigned short* xbase = &LS.xnA[0][0];

    const int blk = blockIdx.x;
    const int b = blk >> 10, tyb = (blk >> 5) & 31, txb = blk & 31;
    const int y0 = tyb * 8, x0 = txb * 8;
    const int tid = threadIdx.x;
    const int wv = tid >> 6;           // wave 0..7
    const int l  = tid & 63;
    const int lm = l & 15;
    const int lq = l >> 4;
    const bool edge = (tyb == 0) | (tyb == 31) | (txb == 0) | (txb == 31);

    // ---- FC1 weight B-frags: wave (cb, mhalf) ----
    const int cb = wv >> 1, mhalf = wv & 1;
    const half8v bf0 = *(const half8v*)&w1p[(cb * 32 + lm) * 32 + lq * 8];
    const half8v bf1 = *(const half8v*)&w1p[(cb * 32 + 16 + lm) * 32 + lq * 8];

    // ---- P0: LN2, 4 threads per halo pixel (8 ch each) ----
    if (tid < 400) {
        const int px = tid >> 2, q4 = tid & 3;
        const int hy = px / 10, hx = px % 10;
        const int iy = y0 + hy - 1, ix = x0 + hx - 1;
        const bool inb = (iy >= 0 && iy < IMG && ix >= 0 && ix < IMG);
        unsigned pk[4];
        if (inb) {
            const size_t base = ((size_t)b * HWTOK + iy * IMG + ix) * CH + q4 * 8;
            const float4* xp = (const float4*)(x1 + base);
            float v[8];
            float s = 0.f;
            #pragma unroll
            for (int i = 0; i < 2; ++i) {
                const float4 t = xp[i];
                v[i*4+0]=t.x; v[i*4+1]=t.y; v[i*4+2]=t.z; v[i*4+3]=t.w;
                s += t.x + t.y + t.z + t.w;
            }
            s += __shfl_xor(s, 1);
            s += __shfl_xor(s, 2);
            const float mu = s * (1.f / 32.f);
            float qq = 0.f;
            #pragma unroll
            for (int c = 0; c < 8; ++c) { const float d = v[c]-mu; qq += d*d; }
            qq += __shfl_xor(qq, 1);
            qq += __shfl_xor(qq, 2);
            const float inv = rsqrtf(qq * (1.f/32.f) + 1e-5f);
            #pragma unroll
            for (int j = 0; j < 4; ++j) {
                const int c = q4 * 8 + 2 * j;
                pk[j] = packh2((v[2*j]   - mu) * inv * n2g[c]   + n2b[c],
                               (v[2*j+1] - mu) * inv * n2g[c+1] + n2b[c+1]);
            }
        } else {
            #pragma unroll
            for (int j = 0; j < 4; ++j) pk[j] = 0u;
        }
        #pragma unroll
        for (int j = 0; j < 4; ++j)
            *(unsigned*)&LS.xnA[px][q4 * 8 + 2 * j] = pk[j];
    }
    __syncthreads();

    // ---- P1: FC1 MFMA (bias in C) -> packed GELU -> hid; own mt half ----
    {
        const int c0 = cb * 32 + 2 * lm;
        const float bias0 = b1[c0], bias1 = b1[c0 + 1];
        const floatx4 cb0 = {bias0, bias0, bias0, bias0};
        const floatx4 cb1 = {bias1, bias1, bias1, bias1};
        const int mt0 = mhalf ? 4 : 0;
        const int mtN = mhalf ? 7 : 4;
        for (int mt = mt0; mt < mtN; ++mt) {
            const half8v af = ld8_b32(xbase + (mt * 16 + lm) * 34 + lq * 8);
            floatx4 a0 = __builtin_amdgcn_mfma_f32_16x16x32_f16(af, bf0, cb0, 0, 0, 0);
            floatx4 a1 = __builtin_amdgcn_mfma_f32_16x16x32_f16(af, bf1, cb1, 0, 0, 0);
            #pragma unroll
            for (int r = 0; r < 4; ++r) {
                const int p = mt * 16 + lq * 4 + r;
                if (mt < 6 || p < 100) {
                    half2v g = gelu2v(pkrtz(a0[r], a1[r]));
                    unsigned int bits = __builtin_bit_cast(unsigned int, g);
                    if (edge) {
                        const int hy = (p * 205) >> 11;
                        const int hx = p - hy * 10;
                        const int iy = y0 + hy - 1, ix = x0 + hx - 1;
                        const bool inb = (iy >= 0) & (iy < IMG) & (ix >= 0) & (ix < IMG);
                        if (!inb) bits = 0u;
                    }
                    *(unsigned int*)&LS.hg.hid[p][c0] = bits;
                }
            }
        }
    }
    __syncthreads();

    // ---- P2: dwconv 3x3, 2 channels/thread, row-blocked -> glA ----
    {
        const int jq = tid & 63, pg = tid >> 6;    // j0 = 2*jq; row pg
        const int j0 = 2 * jq;
        half2v dwa[9];
        #pragma unroll
        for (int t = 0; t < 9; ++t)
            dwa[t] = __builtin_bit_cast(half2v, *(const unsigned*)&dwp[t * 128 + j0]);
        half2v acc[8];
        {
            const half2v dba = __builtin_bit_cast(half2v, *(const unsigned*)&dwbp[j0]);
            #pragma unroll
            for (int i = 0; i < 8; ++i) acc[i] = dba;
        }
        #pragma unroll
        for (int ky = 0; ky < 3; ++ky) {
            unsigned rr[10];
            #pragma unroll
            for (int cx = 0; cx < 10; ++cx)
                rr[cx] = *(const unsigned*)&LS.hg.hid[(pg + ky) * 10 + cx][j0];
            #pragma unroll
            for (int i = 0; i < 8; ++i)
                #pragma unroll
                for (int kx = 0; kx < 3; ++kx)
                    acc[i] = __builtin_bit_cast(half2v, rr[i + kx]) * dwa[ky*3+kx] + acc[i];
        }
        __syncthreads();          // ALL hid reads complete; glA may alias hid
        #pragma unroll
        for (int i = 0; i < 8; ++i) {
            const half2v g = gelu2v(acc[i]);
            *(unsigned*)&LS.hg.glA[pg * 8 + i][j0] = __builtin_bit_cast(unsigned, g);
        }
    }
    __syncthreads();

    // ---- P3: FC2 MFMA (K=128, bias in C) + residual; one quadrant/wave ----
    {
        const int mt = wv >> 1, nt = wv & 1;
        half8v w2f[4];
        #pragma unroll
        for (int kc = 0; kc < 4; ++kc)
            w2f[kc] = *(const half8v*)&w2p[(nt*16 + lm) * 128 + kc*32 + lq*8];
        const int c = nt * 16 + lm;
        const float bias = b2[c];
        floatx4 acc = {bias, bias, bias, bias};
        #pragma unroll
        for (int kc = 0; kc < 4; ++kc) {
            const half8v a = ld8_b64(&LS.hg.glA[mt * 16 + lm][kc * 32 + lq * 8]);
            acc = __builtin_amdgcn_mfma_f32_16x16x32_f16(a, w2f[kc], acc, 0, 0, 0);
        }
        #pragma unroll
        for (int r = 0; r < 4; ++r) {
            const int p = mt * 16 + lq * 4 + r;
            const int iy = y0 + (p >> 3), ix = x0 + (p & 7);
            const size_t g = ((size_t)b * HWTOK + iy * IMG + ix) * CH + c;
            out[g] = x1[g] + acc[r];
        }
    }
}

// ---------------------------------------------------------------------------
extern "C" void kernel_launch(void* const* d_in, const int* in_sizes, int n_in,
                              void* d_out, int out_size, void* d_ws, size_t ws_size,
                              hipStream_t stream)
{
    const float* x    = (const float*)d_in[0];
    const float* n1g  = (const float*)d_in[1];
    const float* n1b  = (const float*)d_in[2];
    const float* wq   = (const float*)d_in[3];
    const float* bq   = (const float*)d_in[4];
    const float* wkv  = (const float*)d_in[5];
    const float* bkv  = (const float*)d_in[6];
    const float* wo   = (const float*)d_in[7];
    const float* bo   = (const float*)d_in[8];
    const float* relb = (const float*)d_in[9];
    const float* n2g  = (const float*)d_in[10];
    const float* n2b  = (const float*)d_in[11];
    const float* w1   = (const float*)d_in[12];
    const float* b1   = (const float*)d_in[13];
    const float* dw   = (const float*)d_in[14];
    const float* dwb  = (const float*)d_in[15];
    const float* w2   = (const float*)d_in[16];
    const float* b2   = (const float*)d_in[17];

    float* out = (float*)d_out;
    float* x1  = (float*)d_ws;                       // 64 MB
    char* base = (char*)d_ws + (size_t)8 * HWTOK * CH * 4;
    unsigned short* w1p  = (unsigned short*)(base);           // 8192 B
    unsigned short* w2p  = (unsigned short*)(base + 8192);    // 8192 B
    unsigned short* wqp  = (unsigned short*)(base + 16384);   // 2048 B
    unsigned short* wkp  = (unsigned short*)(base + 18432);   // 2048 B
    unsigned short* wvp  = (unsigned short*)(base + 20480);   // 2048 B
    unsigned short* wop  = (unsigned short*)(base + 22528);   // 2048 B
    unsigned short* dwp  = (unsigned short*)(base + 24576);   // 2304 B
    unsigned short* dwbp = (unsigned short*)(base + 26880);   // 256 B
    float*          bias = (float*)(base + 28672);            // 32768 B

    prep_kernel<<<29, 256, 0, stream>>>(w1, w2, wq, wkv, wo, dw, dwb, relb,
                                        w1p, w2p, wqp, wkp, wvp, wop,
                                        dwp, dwbp, bias);
    attn_kernel<<<8192, 256, 0, stream>>>(x, n1g, n1b, bq, bkv, bo,
                                          wqp, wkp, wvp, wop,
                                          (const float4*)bias, x1);
    leff_kernel_gw<<<8192, 512, 0, stream>>>(x1, n2g, n2b, b1, b2,
                                             w1p, w2p, dwp, dwbp, out);
}

// Round 18
// 132.108 us; speedup vs baseline: 1.0010x; 1.0010x over previous
//
#include <hip/hip_runtime.h>
#include <hip/hip_bf16.h>
#include <math.h>

// Problem constants (B=8, H=W=256, C=32, WIN=8, HEADS=2, DH=16, HIDDEN=128)
#define IMG   256
#define HWTOK 65536
#define CH    32

typedef __attribute__((ext_vector_type(8))) _Float16 half8v;    // 8 fp16
typedef __attribute__((ext_vector_type(2))) _Float16 half2v;    // 2 fp16
typedef __attribute__((ext_vector_type(4))) float floatx4;

__device__ __forceinline__ unsigned short f2h(float f) {
    _Float16 h = (_Float16)f;
    return __builtin_bit_cast(unsigned short, h);
}
__device__ __forceinline__ half2v pkrtz(float a, float b) {
    return __builtin_bit_cast(half2v, __builtin_amdgcn_cvt_pkrtz(a, b));
}
__device__ __forceinline__ unsigned packh2(float a, float b) {
    return __builtin_bit_cast(unsigned, __builtin_amdgcn_cvt_pkrtz(a, b));
}
// 16B fragment loads from LDS rows whose stride only guarantees 4B / 8B align.
__device__ __forceinline__ half8v ld8_b32(const unsigned short* p) {
    uint4 u;
    u.x = *(const unsigned*)(p + 0);
    u.y = *(const unsigned*)(p + 2);
    u.z = *(const unsigned*)(p + 4);
    u.w = *(const unsigned*)(p + 6);
    return __builtin_bit_cast(half8v, u);
}
__device__ __forceinline__ half8v ld8_b64(const unsigned short* p) {
    const uint2 a = *(const uint2*)(p + 0);
    const uint2 b = *(const uint2*)(p + 4);
    uint4 u; u.x = a.x; u.y = a.y; u.z = b.x; u.w = b.y;
    return __builtin_bit_cast(half8v, u);
}

// GELU via odd Taylor of Phi(v) = 0.5 + v*p(v^2), packed fp16.
__device__ __forceinline__ half2v gelu2v(half2v v) {
    const half2v hi = (half2v)(_Float16)( 2.0f);
    const half2v lo = (half2v)(_Float16)(-2.0f);
    const half2v vc = __builtin_elementwise_min(__builtin_elementwise_max(v, lo), hi);
    const half2v s  = vc * vc;
    half2v p = s * (half2v)(_Float16)(-1.18726e-3f) + (half2v)(_Float16)(9.97356e-3f);
    p = s * p + (half2v)(_Float16)(-6.64904e-2f);
    p = s * p + (half2v)(_Float16)( 3.989423e-1f);
    return v * (vc * p + (half2v)(_Float16)(0.5f));
}

// ---------------------------------------------------------------------------
// Prep: one-shot marshalling into workspace (29 blocks x 256). (unchanged)
// ---------------------------------------------------------------------------
__global__ __launch_bounds__(256) void prep_kernel(
    const float* __restrict__ w1, const float* __restrict__ w2,
    const float* __restrict__ wq, const float* __restrict__ wkv,
    const float* __restrict__ wo, const float* __restrict__ dw,
    const float* __restrict__ dwb, const float* __restrict__ relb,
    unsigned short* __restrict__ w1p, unsigned short* __restrict__ w2p,
    unsigned short* __restrict__ wqp, unsigned short* __restrict__ wkp,
    unsigned short* __restrict__ wvp, unsigned short* __restrict__ wop,
    unsigned short* __restrict__ dwp, unsigned short* __restrict__ dwbp,
    float* __restrict__ biasf)
{
    const float LOG2E = 1.4426950408889634f;
    const float QSC   = 0.25f * LOG2E;
    const int bid = blockIdx.x, tid = threadIdx.x;

    if (bid < 16) {                       // leff FC weights
        const int t = bid * 256 + tid;
        const int row = t >> 5, k = t & 31;
        const int bl = row >> 5, wi = row & 31;
        const int j = bl * 32 + ((wi & 15) << 1) + (wi >> 4);
        w1p[t] = f2h(w1[k * 128 + j]);
        const int n = t >> 7, kk = t & 127;
        w2p[t] = f2h(w2[kk * 32 + n]);
    } else if (bid < 20) {                // attn weights, frag layout
        const int u = (bid - 16) * 256 + tid;
        const int h = u >> 9, rem = u & 511;
        const int col = rem >> 5, k = rem & 31;
        wqp[u] = f2h(wq [k * 32 + h * 16 + col] * QSC);
        wkp[u] = f2h(wkv[k * 64 + h * 16 + col]);
        wvp[u] = f2h(wkv[k * 64 + 32 + h * 16 + col]);
        const int n = u >> 5, kk2 = u & 31;
        wop[u] = f2h(wo[kk2 * 32 + n]);
    } else if (bid < 28) {                // bias C-fragment table
        const int g = (bid - 20) * 256 + tid;
        const int h = g >> 10, nt = (g >> 8) & 3, mt = (g >> 6) & 3, l = g & 63;
        const int q = nt * 16 + (l & 15);
        const int mb = mt * 16 + (l >> 4) * 4;
        const int qy = q >> 3, qx = q & 7;
        #pragma unroll
        for (int r = 0; r < 4; ++r) {
            const int m = mb + r;
            const int my = m >> 3, mx = m & 7;
            const int idx = (qy - my + 7) * 15 + (qx - mx + 7);
            biasf[g * 4 + r] = relb[idx * 2 + h] * LOG2E;
        }
    } else {                              // dw pack
        for (int e = tid; e < 1280; e += 256) {
            if (e < 1152) dwp[e] = f2h(dw[(e & 127) * 9 + (e >> 7)]);
            else          dwbp[e - 1152] = f2h(dwb[e - 1152]);
        }
    }
}

// ---------------------------------------------------------------------------
// Kernel 1: LN1 + window attention + proj + residual.
// ONE window per 256-thread block (4 waves = (head h, half s2)).
// LDS squeezed to EXACTLY 32,768 B -> 4 blocks/CU under the 128 KB pool
// model (was 34,816 -> 3 blocks).  Strides: xn/O/Q 38, P 68, K 48, VT 68;
// fragment loads use b64/b32 splits where 16B alignment is lost.  denom
// aliases the dead Q region (barrier added after S^T fragment loads).
// ---------------------------------------------------------------------------
__global__ __launch_bounds__(256, 4) void attn_kernel(
    const float* __restrict__ x,
    const float* __restrict__ n1g, const float* __restrict__ n1b,
    const float* __restrict__ bq,  const float* __restrict__ bkv,
    const float* __restrict__ bo,
    const unsigned short* __restrict__ wqp,
    const unsigned short* __restrict__ wkp,
    const unsigned short* __restrict__ wvp,
    const unsigned short* __restrict__ wop,
    const float4* __restrict__ biasf4,
    float* __restrict__ x1)
{
    struct Win {
        union {
            unsigned short xn[64][38];    // 4864
            unsigned short P[2][64][68];  // 17408 (max member)
            unsigned short O[64][38];
        } u;
        unsigned short Q[64][38];         // 4864 (denom aliases after S^T loads)
        unsigned short K[64][48];         // 6144 (cols 16..31 zero mask)
        unsigned short VT[2][16][68];     // 4352
    };                                    // total 32768 B exactly
    __shared__ __align__(16) Win S;

    const int tid = threadIdx.x;
    const int wv  = tid >> 6;             // wave 0..3
    const int h   = wv & 1;               // head
    const int s2  = wv >> 1;              // half: mt/nt in {2*s2, 2*s2+1}
    const int l   = tid & 63;
    const int lm  = l & 15, lq = l >> 4;

    const int win = blockIdx.x;
    const int b   = win >> 10;
    const int wh  = (win >> 5) & 31, ww = win & 31;
    const size_t wbase = ((size_t)b * HWTOK + (wh * 8) * IMG + ww * 8) * CH;

    const float LOG2E = 1.4426950408889634f;
    const float QSC   = 0.25f * LOG2E;

    // ---- weight B-frags: single b128 loads from prepped tables ----
    const half8v bwq  = *(const half8v*)&wqp[h * 512 + lm * 32 + lq * 8];
    const half8v bwk  = *(const half8v*)&wkp[h * 512 + lm * 32 + lq * 8];
    const half8v bwv  = *(const half8v*)&wvp[h * 512 + lm * 32 + lq * 8];
    const half8v bwo0 = *(const half8v*)&wop[lm * 32 + lq * 8];
    const half8v bwo1 = *(const half8v*)&wop[(16 + lm) * 32 + lq * 8];

    // ---- LN staging: 4 threads per token (8 ch each, 2-level shfl) ----
    {
        const int tok = tid >> 2, q4 = tid & 3;
        const size_t sbase = wbase
            + (size_t)((tok >> 3) * IMG + (tok & 7)) * CH + q4 * 8;
        const float4* xp = (const float4*)(x + sbase);
        float v[8];
        float s = 0.f;
        #pragma unroll
        for (int i = 0; i < 2; ++i) {
            const float4 t = xp[i];
            v[i*4+0]=t.x; v[i*4+1]=t.y; v[i*4+2]=t.z; v[i*4+3]=t.w;
            s += t.x + t.y + t.z + t.w;
        }
        s += __shfl_xor(s, 1);
        s += __shfl_xor(s, 2);
        const float mu = s * (1.f / 32.f);
        float qq = 0.f;
        #pragma unroll
        for (int c = 0; c < 8; ++c) { const float d = v[c] - mu; qq += d * d; }
        qq += __shfl_xor(qq, 1);
        qq += __shfl_xor(qq, 2);
        const float inv = rsqrtf(qq * (1.f / 32.f) + 1e-5f);
        #pragma unroll
        for (int j = 0; j < 4; ++j) {
            const int c = q4 * 8 + 2 * j;
            *(unsigned*)&S.u.xn[tok][c] =
                packh2((v[2*j]   - mu) * inv * n1g[c]   + n1b[c],
                       (v[2*j+1] - mu) * inv * n1g[c+1] + n1b[c+1]);
        }
        if (q4 < 2) {                                // zero K mask cols 16..31
            const uint4 z = {0u, 0u, 0u, 0u};
            *(uint4*)&S.K[tok][16 + q4 * 8] = z;     // 96tok+32+16q4: 16B ok
        }
    }
    __syncthreads();                               // (1) xn ready

    const float bqv = bq[h*16 + lm] * QSC;
    const float bkv_ = bkv[h*16 + lm];
    const float bvv = bkv[32 + h*16 + lm];
    const floatx4 cq = {bqv, bqv, bqv, bqv};
    const floatx4 ck = {bkv_, bkv_, bkv_, bkv_};
    const floatx4 cv = {bvv, bvv, bvv, bvv};
    const floatx4 zero = {0.f, 0.f, 0.f, 0.f};

    // ---- QKV projection (own head, own mt half) ----
    #pragma unroll
    for (int mi = 0; mi < 2; ++mi) {
        const int mt = 2*s2 + mi;
        const half8v a = ld8_b32(&S.u.xn[mt*16 + lm][lq*8]);
        const floatx4 dq = __builtin_amdgcn_mfma_f32_16x16x32_f16(a, bwq, cq, 0,0,0);
        const floatx4 dk = __builtin_amdgcn_mfma_f32_16x16x32_f16(a, bwk, ck, 0,0,0);
        const floatx4 dv = __builtin_amdgcn_mfma_f32_16x16x32_f16(a, bwv, cv, 0,0,0);
        const int r0 = mt*16 + lq*4;
        #pragma unroll
        for (int r = 0; r < 4; ++r) {
            S.Q[r0 + r][h*16 + lm] = f2h(dq[r]);
            S.K[r0 + r][h*32 + lm] = f2h(dk[r]);   // head h dims at cols 32h
        }
        uint2 vv;
        vv.x = packh2(dv[0], dv[1]);
        vv.y = packh2(dv[2], dv[3]);
        *(uint2*)&S.VT[h][lm][r0] = vv;            // 136lm+2r0: 8B aligned
    }
    __syncthreads();                               // (2) Q/K/V complete

    // ---- load S^T fragments, then free Q region for denom ----
    half8v ak[4], bqf[2];
    #pragma unroll
    for (int mt = 0; mt < 4; ++mt)
        ak[mt] = *(const half8v*)&S.K[mt*16 + lm][h*16 + lq*8];  // 96row: 16B ok
    #pragma unroll
    for (int ni = 0; ni < 2; ++ni)
        bqf[ni] = ld8_b32(&S.Q[(2*s2 + ni)*16 + lm][lq*8]);
    __syncthreads();                               // (3) frags in regs; Q dead

    float* denomQ = (float*)&S.Q[0][0];            // [h*64 + i]

    // ---- S^T = mfma(K, Q), rel_bias via C-init; own nt half ----
    #pragma unroll
    for (int ni = 0; ni < 2; ++ni) {
        const int nt = 2*s2 + ni;
        float sum = 0.f;
        #pragma unroll
        for (int mt = 0; mt < 4; ++mt) {
            const float4 cb = biasf4[(h*16 + nt*4 + mt) * 64 + l];
            const floatx4 C = {cb.x, cb.y, cb.z, cb.w};
            const floatx4 d = __builtin_amdgcn_mfma_f32_16x16x32_f16(ak[mt], bqf[ni], C, 0,0,0);
            const float e0 = exp2f(d[0]);
            const float e1 = exp2f(d[1]);
            const float e2 = exp2f(d[2]);
            const float e3 = exp2f(d[3]);
            sum += (e0 + e1) + (e2 + e3);
            uint2 pw;
            pw.x = packh2(e0, e1);
            pw.y = packh2(e2, e3);
            *(uint2*)&S.u.P[h][nt*16 + lm][mt*16 + lq*4] = pw;   // 8B aligned
        }
        sum += __shfl_xor(sum, 16);
        sum += __shfl_xor(sum, 32);
        if (l < 16) denomQ[h*64 + nt*16 + l] = __frcp_rn(sum);
    }

    // ---- PV + normalize (own mt half; P rows + denom are wave-local) ----
    const half8v bva = ld8_b64(&S.VT[h][lm][lq*8]);
    const half8v bvb = ld8_b64(&S.VT[h][lm][32 + lq*8]);
    float oreg[8];
    #pragma unroll
    for (int mi = 0; mi < 2; ++mi) {
        const int mt = 2*s2 + mi;
        const half8v ap0 = ld8_b64(&S.u.P[h][mt*16 + lm][lq*8]);
        const half8v ap1 = ld8_b64(&S.u.P[h][mt*16 + lm][32 + lq*8]);
        floatx4 ov = __builtin_amdgcn_mfma_f32_16x16x32_f16(ap0, bva, zero, 0,0,0);
        ov         = __builtin_amdgcn_mfma_f32_16x16x32_f16(ap1, bvb, ov,   0,0,0);
        const float4 dn = *(const float4*)&denomQ[h*64 + mt*16 + lq*4];
        oreg[mi*4+0] = ov[0] * dn.x;
        oreg[mi*4+1] = ov[1] * dn.y;
        oreg[mi*4+2] = ov[2] * dn.z;
        oreg[mi*4+3] = ov[3] * dn.w;
    }
    __syncthreads();                 // (4) PV reads done before O clobbers P

    #pragma unroll
    for (int mi = 0; mi < 2; ++mi) {
        const int mt = 2*s2 + mi;
        #pragma unroll
        for (int r = 0; r < 4; ++r)
            S.u.O[mt*16 + lq*4 + r][h*16 + lm] = f2h(oreg[mi*4 + r]);
    }
    __syncthreads();                 // (5) O complete

    // ---- out-projection + residual: wave wv handles mt = wv ----
    {
        const int mt = wv;
        const float bo0 = bo[lm], bo1 = bo[16 + lm];
        const floatx4 co0 = {bo0, bo0, bo0, bo0};
        const floatx4 co1 = {bo1, bo1, bo1, bo1};
        const half8v aO = ld8_b32(&S.u.O[mt*16 + lm][lq*8]);
        const floatx4 d0 = __builtin_amdgcn_mfma_f32_16x16x32_f16(aO, bwo0, co0, 0,0,0);
        const floatx4 d1 = __builtin_amdgcn_mfma_f32_16x16x32_f16(aO, bwo1, co1, 0,0,0);
        #pragma unroll
        for (int r = 0; r < 4; ++r) {
            const int t = mt*16 + lq*4 + r;
            const size_t g = wbase + (size_t)((t >> 3) * IMG + (t & 7)) * CH;
            x1[g + lm]      = x[g + lm]      + d0[r];
            x1[g + 16 + lm] = x[g + 16 + lm] + d1[r];
        }
    }
}

// ---------------------------------------------------------------------------
// Kernel 2: fused LeFF — 512 threads, LDS squeezed to 32,400 B (xnA stride 34,
// pad rows deleted: mt=6 A-frag reads spill into hid; the garbage only feeds
// MFMA D-rows p>=100 which are discarded) -> 4 blocks/CU = 32 waves = 100%.
// ---------------------------------------------------------------------------
__global__ __launch_bounds__(512, 8) void leff_kernel_gw(
    const float* __restrict__ x1,
    const float* __restrict__ n2g, const float* __restrict__ n2b,
    const float* __restrict__ b1,  const float* __restrict__ b2,
    const unsigned short* __restrict__ w1p,
    const unsigned short* __restrict__ w2p,
    const unsigned short* __restrict__ dwp,
    const unsigned short* __restrict__ dwbp,
    float* __restrict__ out)
{
    struct LeffS {
        unsigned short xnA[100][34];    // 6800 B (A-frag reads may spill ->hg)
        union {
            unsigned short hid[100][128];   // 25600 B
            unsigned short glA[64][132];    // 16896 B (inside hid region)
        } hg;
    };                                   // 32400 B total
    __shared__ __align__(16) LeffS LS;
    const unsigned short* xbase = &LS.xnA[0][0];

    const int blk = blockIdx.x;
    const int b = blk >> 10, tyb = (blk >> 5) & 31, txb = blk & 31;
    const int y0 = tyb * 8, x0 = txb * 8;
    const int tid = threadIdx.x;
    const int wv = tid >> 6;           // wave 0..7
    const int l  = tid & 63;
    const int lm = l & 15;
    const int lq = l >> 4;
    const bool edge = (tyb == 0) | (tyb == 31) | (txb == 0) | (txb == 31);

    // ---- FC1 weight B-frags: wave (cb, mhalf) ----
    const int cb = wv >> 1, mhalf = wv & 1;
    const half8v bf0 = *(const half8v*)&w1p[(cb * 32 + lm) * 32 + lq * 8];
    const half8v bf1 = *(const half8v*)&w1p[(cb * 32 + 16 + lm) * 32 + lq * 8];

    // ---- P0: LN2, 4 threads per halo pixel (8 ch each) ----
    if (tid < 400) {
        const int px = tid >> 2, q4 = tid & 3;
        const int hy = px / 10, hx = px % 10;
        const int iy = y0 + hy - 1, ix = x0 + hx - 1;
        const bool inb = (iy >= 0 && iy < IMG && ix >= 0 && ix < IMG);
        unsigned pk[4];
        if (inb) {
            const size_t base = ((size_t)b * HWTOK + iy * IMG + ix) * CH + q4 * 8;
            const float4* xp = (const float4*)(x1 + base);
            float v[8];
            float s = 0.f;
            #pragma unroll
            for (int i = 0; i < 2; ++i) {
                const float4 t = xp[i];
                v[i*4+0]=t.x; v[i*4+1]=t.y; v[i*4+2]=t.z; v[i*4+3]=t.w;
                s += t.x + t.y + t.z + t.w;
            }
            s += __shfl_xor(s, 1);
            s += __shfl_xor(s, 2);
            const float mu = s * (1.f / 32.f);
            float qq = 0.f;
            #pragma unroll
            for (int c = 0; c < 8; ++c) { const float d = v[c]-mu; qq += d*d; }
            qq += __shfl_xor(qq, 1);
            qq += __shfl_xor(qq, 2);
            const float inv = rsqrtf(qq * (1.f/32.f) + 1e-5f);
            #pragma unroll
            for (int j = 0; j < 4; ++j) {
                const int c = q4 * 8 + 2 * j;
                pk[j] = packh2((v[2*j]   - mu) * inv * n2g[c]   + n2b[c],
                               (v[2*j+1] - mu) * inv * n2g[c+1] + n2b[c+1]);
            }
        } else {
            #pragma unroll
            for (int j = 0; j < 4; ++j) pk[j] = 0u;
        }
        #pragma unroll
        for (int j = 0; j < 4; ++j)
            *(unsigned*)&LS.xnA[px][q4 * 8 + 2 * j] = pk[j];
    }
    __syncthreads();

    // ---- P1: FC1 MFMA (bias in C) -> packed GELU -> hid; own mt half ----
    {
        const int c0 = cb * 32 + 2 * lm;
        const float bias0 = b1[c0], bias1 = b1[c0 + 1];
        const floatx4 cb0 = {bias0, bias0, bias0, bias0};
        const floatx4 cb1 = {bias1, bias1, bias1, bias1};
        const int mt0 = mhalf ? 4 : 0;
        const int mtN = mhalf ? 7 : 4;
        for (int mt = mt0; mt < mtN; ++mt) {
            const half8v af = ld8_b32(xbase + (mt * 16 + lm) * 34 + lq * 8);
            floatx4 a0 = __builtin_amdgcn_mfma_f32_16x16x32_f16(af, bf0, cb0, 0, 0, 0);
            floatx4 a1 = __builtin_amdgcn_mfma_f32_16x16x32_f16(af, bf1, cb1, 0, 0, 0);
            #pragma unroll
            for (int r = 0; r < 4; ++r) {
                const int p = mt * 16 + lq * 4 + r;
                if (mt < 6 || p < 100) {
                    half2v g = gelu2v(pkrtz(a0[r], a1[r]));
                    unsigned int bits = __builtin_bit_cast(unsigned int, g);
                    if (edge) {
                        const int hy = (p * 205) >> 11;
                        const int hx = p - hy * 10;
                        const int iy = y0 + hy - 1, ix = x0 + hx - 1;
                        const bool inb = (iy >= 0) & (iy < IMG) & (ix >= 0) & (ix < IMG);
                        if (!inb) bits = 0u;
                    }
                    *(unsigned int*)&LS.hg.hid[p][c0] = bits;
                }
            }
        }
    }
    __syncthreads();

    // ---- P2: dwconv 3x3, 2 channels/thread, row-blocked -> glA ----
    {
        const int jq = tid & 63, pg = tid >> 6;    // j0 = 2*jq; row pg
        const int j0 = 2 * jq;
        half2v dwa[9];
        #pragma unroll
        for (int t = 0; t < 9; ++t)
            dwa[t] = __builtin_bit_cast(half2v, *(const unsigned*)&dwp[t * 128 + j0]);
        half2v acc[8];
        {
            const half2v dba = __builtin_bit_cast(half2v, *(const unsigned*)&dwbp[j0]);
            #pragma unroll
            for (int i = 0; i < 8; ++i) acc[i] = dba;
        }
        #pragma unroll
        for (int ky = 0; ky < 3; ++ky) {
            unsigned rr[10];
            #pragma unroll
            for (int cx = 0; cx < 10; ++cx)
                rr[cx] = *(const unsigned*)&LS.hg.hid[(pg + ky) * 10 + cx][j0];
            #pragma unroll
            for (int i = 0; i < 8; ++i)
                #pragma unroll
                for (int kx = 0; kx < 3; ++kx)
                    acc[i] = __builtin_bit_cast(half2v, rr[i + kx]) * dwa[ky*3+kx] + acc[i];
        }
        __syncthreads();          // ALL hid reads complete; glA may alias hid
        #pragma unroll
        for (int i = 0; i < 8; ++i) {
            const half2v g = gelu2v(acc[i]);
            *(unsigned*)&LS.hg.glA[pg * 8 + i][j0] = __builtin_bit_cast(unsigned, g);
        }
    }
    __syncthreads();

    // ---- P3: FC2 MFMA (K=128, bias in C) + residual; one quadrant/wave ----
    {
        const int mt = wv >> 1, nt = wv & 1;
        half8v w2f[4];
        #pragma unroll
        for (int kc = 0; kc < 4; ++kc)
            w2f[kc] = *(const half8v*)&w2p[(nt*16 + lm) * 128 + kc*32 + lq*8];
        const int c = nt * 16 + lm;
        const float bias = b2[c];
        floatx4 acc = {bias, bias, bias, bias};
        #pragma unroll
        for (int kc = 0; kc < 4; ++kc) {
            const half8v a = ld8_b64(&LS.hg.glA[mt * 16 + lm][kc * 32 + lq * 8]);
            acc = __builtin_amdgcn_mfma_f32_16x16x32_f16(a, w2f[kc], acc, 0, 0, 0);
        }
        #pragma unroll
        for (int r = 0; r < 4; ++r) {
            const int p = mt * 16 + lq * 4 + r;
            const int iy = y0 + (p >> 3), ix = x0 + (p & 7);
            const size_t g = ((size_t)b * HWTOK + iy * IMG + ix) * CH + c;
            out[g] = x1[g] + acc[r];
        }
    }
}

// ---------------------------------------------------------------------------
extern "C" void kernel_launch(void* const* d_in, const int* in_sizes, int n_in,
                              void* d_out, int out_size, void* d_ws, size_t ws_size,
                              hipStream_t stream)
{
    const float* x    = (const float*)d_in[0];
    const float* n1g  = (const float*)d_in[1];
    const float* n1b  = (const float*)d_in[2];
    const float* wq   = (const float*)d_in[3];
    const float* bq   = (const float*)d_in[4];
    const float* wkv  = (const float*)d_in[5];
    const float* bkv  = (const float*)d_in[6];
    const float* wo   = (const float*)d_in[7];
    const float* bo   = (const float*)d_in[8];
    const float* relb = (const float*)d_in[9];
    const float* n2g  = (const float*)d_in[10];
    const float* n2b  = (const float*)d_in[11];
    const float* w1   = (const float*)d_in[12];
    const float* b1   = (const float*)d_in[13];
    const float* dw   = (const float*)d_in[14];
    const float* dwb  = (const float*)d_in[15];
    const float* w2   = (const float*)d_in[16];
    const float* b2   = (const float*)d_in[17];

    float* out = (float*)d_out;
    float* x1  = (float*)d_ws;                       // 64 MB
    char* base = (char*)d_ws + (size_t)8 * HWTOK * CH * 4;
    unsigned short* w1p  = (unsigned short*)(base);           // 8192 B
    unsigned short* w2p  = (unsigned short*)(base + 8192);    // 8192 B
    unsigned short* wqp  = (unsigned short*)(base + 16384);   // 2048 B
    unsigned short* wkp  = (unsigned short*)(base + 18432);   // 2048 B
    unsigned short* wvp  = (unsigned short*)(base + 20480);   // 2048 B
    unsigned short* wop  = (unsigned short*)(base + 22528);   // 2048 B
    unsigned short* dwp  = (unsigned short*)(base + 24576);   // 2304 B
    unsigned short* dwbp = (unsigned short*)(base + 26880);   // 256 B
    float*          bias = (float*)(base + 28672);            // 32768 B

    prep_kernel<<<29, 256, 0, stream>>>(w1, w2, wq, wkv, wo, dw, dwb, relb,
                                        w1p, w2p, wqp, wkp, wvp, wop,
                                        dwp, dwbp, bias);
    attn_kernel<<<8192, 256, 0, stream>>>(x, n1g, n1b, bq, bkv, bo,
                                          wqp, wkp, wvp, wop,
                                          (const float4*)bias, x1);
    leff_kernel_gw<<<8192, 512, 0, stream>>>(x1, n2g, n2b, b1, b2,
                                             w1p, w2p, dwp, dwbp, out);
}